// Round 1
// baseline (1003.919 us; speedup 1.0000x reference)
//
#include <hip/hip_runtime.h>
#include <math.h>

#define T_SEQ  4096
#define CEMB   1024
#define CHEAD  64
#define NBATCH 8
#define TILE   64
#define LDSP   68   // 64 + 4 pad (keeps float4 alignment, breaks bank strides)

// ---------------------------------------------------------------------------
// Kernel 1: fused QKV projection.  C[32768,64] = x[32768,1024] @ W[1024,64]
// blockIdx.y selects (W, out): 0->(Wq,Q) 1->(Wk,K) 2->(Wv,V)
// 64x64 output tile per block, BK=32, 4x4 microtile per thread.
// ---------------------------------------------------------------------------
__global__ __launch_bounds__(256) void proj_kernel(
    const float* __restrict__ x,  const float* __restrict__ Wk,
    const float* __restrict__ Wq, const float* __restrict__ Wv,
    float* __restrict__ Qw, float* __restrict__ Kw, float* __restrict__ Vw)
{
    __shared__ float xsT[32][LDSP];   // [c][row]  (transposed x tile)
    __shared__ float wsm[32][LDSP];   // [c][n]
    const int which = blockIdx.y;
    const float* W = (which == 0) ? Wq : (which == 1) ? Wk : Wv;
    float* outp    = (which == 0) ? Qw : (which == 1) ? Kw : Vw;
    const int row0 = blockIdx.x * 64;
    const int tid = threadIdx.x;
    const int tx = tid & 15, ty = tid >> 4;

    float acc[4][4] = {};
    for (int c0 = 0; c0 < CEMB; c0 += 32) {
        #pragma unroll
        for (int l = 0; l < 2; ++l) {               // 64x32 x-tile, transposed
            int idx = tid + l * 256;
            int r  = idx >> 3;
            int c4 = (idx & 7) << 2;
            float4 v = *reinterpret_cast<const float4*>(
                x + (size_t)(row0 + r) * CEMB + c0 + c4);
            xsT[c4 + 0][r] = v.x; xsT[c4 + 1][r] = v.y;
            xsT[c4 + 2][r] = v.z; xsT[c4 + 3][r] = v.w;
        }
        #pragma unroll
        for (int l = 0; l < 2; ++l) {               // 32x64 W tile, direct
            int idx = tid + l * 256;
            int c  = idx >> 4;
            int n4 = (idx & 15) << 2;
            *reinterpret_cast<float4*>(&wsm[c][n4]) =
                *reinterpret_cast<const float4*>(W + (size_t)(c0 + c) * CHEAD + n4);
        }
        __syncthreads();
        #pragma unroll
        for (int kk = 0; kk < 32; ++kk) {
            float4 a = *reinterpret_cast<const float4*>(&xsT[kk][ty << 2]);
            float4 b = *reinterpret_cast<const float4*>(&wsm[kk][tx << 2]);
            float av[4] = {a.x, a.y, a.z, a.w};
            float bv[4] = {b.x, b.y, b.z, b.w};
            #pragma unroll
            for (int i = 0; i < 4; ++i)
                #pragma unroll
                for (int j = 0; j < 4; ++j)
                    acc[i][j] = fmaf(av[i], bv[j], acc[i][j]);
        }
        __syncthreads();
    }
    #pragma unroll
    for (int i = 0; i < 4; ++i) {
        float4 o = make_float4(acc[i][0], acc[i][1], acc[i][2], acc[i][3]);
        *reinterpret_cast<float4*>(
            outp + (size_t)(row0 + (ty << 2) + i) * CHEAD + (tx << 2)) = o;
    }
}

// ---------------------------------------------------------------------------
// Kernel 2: column denominators.  Dp[qs][b][k] = partial sum over this
// block's strided q-tiles of exp(s[q,k]*scale) for q >= k.
// grid = (64 k-tiles, 4 q-splits, B).  No max subtraction needed:
// s_max ~ |q|^2/8 <= ~16 -> exp safe in fp32.
// ---------------------------------------------------------------------------
__global__ __launch_bounds__(256) void colsum_kernel(
    const float* __restrict__ Qw, const float* __restrict__ Kw,
    float* __restrict__ Dp)
{
    __shared__ float ksT[CHEAD][LDSP];  // [h][k]
    __shared__ float qsT[CHEAD][LDSP];  // [h][q]
    __shared__ float psT[TILE][LDSP];   // [k][q] holds p = exp
    __shared__ float pd[4][TILE];
    const int kt = blockIdx.x;
    const int qs = blockIdx.y;
    const int b  = blockIdx.z;
    const int k0 = kt * TILE;
    const float* Qb = Qw + (size_t)b * T_SEQ * CHEAD;
    const float* Kb = Kw + (size_t)b * T_SEQ * CHEAD;
    const int tid = threadIdx.x;
    const int tx = tid & 15, ty = tid >> 4;
    const int c = tid & 63, seg = tid >> 6;

    #pragma unroll
    for (int l = 0; l < 4; ++l) {                  // K tile once, transposed
        int idx = tid + l * 256;
        int r  = idx >> 4;
        int h4 = (idx & 15) << 2;
        float4 v = *reinterpret_cast<const float4*>(
            Kb + (size_t)(k0 + r) * CHEAD + h4);
        ksT[h4 + 0][r] = v.x; ksT[h4 + 1][r] = v.y;
        ksT[h4 + 2][r] = v.z; ksT[h4 + 3][r] = v.w;
    }
    float dsum = 0.f;
    __syncthreads();

    for (int q0 = k0 + qs * TILE; q0 < T_SEQ; q0 += 4 * TILE) {
        #pragma unroll
        for (int l = 0; l < 4; ++l) {              // Q tile, transposed
            int idx = tid + l * 256;
            int r  = idx >> 4;
            int h4 = (idx & 15) << 2;
            float4 v = *reinterpret_cast<const float4*>(
                Qb + (size_t)(q0 + r) * CHEAD + h4);
            qsT[h4 + 0][r] = v.x; qsT[h4 + 1][r] = v.y;
            qsT[h4 + 2][r] = v.z; qsT[h4 + 3][r] = v.w;
        }
        __syncthreads();

        float s[4][4] = {};
        #pragma unroll 8
        for (int h = 0; h < CHEAD; ++h) {
            float4 a  = *reinterpret_cast<const float4*>(&qsT[h][ty << 2]);
            float4 bb = *reinterpret_cast<const float4*>(&ksT[h][tx << 2]);
            float av[4] = {a.x, a.y, a.z, a.w};
            float bv[4] = {bb.x, bb.y, bb.z, bb.w};
            #pragma unroll
            for (int i = 0; i < 4; ++i)
                #pragma unroll
                for (int j = 0; j < 4; ++j)
                    s[i][j] = fmaf(av[i], bv[j], s[i][j]);
        }
        #pragma unroll
        for (int j = 0; j < 4; ++j) {              // p = exp(s/8), causal mask
            int kcol = k0 + (tx << 2) + j;
            float pv[4];
            #pragma unroll
            for (int i = 0; i < 4; ++i) {
                int q = q0 + (ty << 2) + i;
                pv[i] = (q >= kcol) ? __expf(s[i][j] * 0.125f) : 0.f;
            }
            *reinterpret_cast<float4*>(&psT[(tx << 2) + j][ty << 2]) =
                make_float4(pv[0], pv[1], pv[2], pv[3]);
        }
        __syncthreads();
        #pragma unroll
        for (int l = 0; l < 4; ++l) {              // column partial sums
            float4 v = *reinterpret_cast<const float4*>(
                &psT[c][(seg << 4) + (l << 2)]);
            dsum += v.x + v.y + v.z + v.w;
        }
        __syncthreads();
    }
    pd[seg][c] = dsum;
    __syncthreads();
    if (tid < 64) {
        float d = pd[0][tid] + pd[1][tid] + pd[2][tid] + pd[3][tid];
        Dp[((size_t)qs * NBATCH + b) * T_SEQ + k0 + tid] = d;
    }
}

// ---------------------------------------------------------------------------
// Kernel 3: output.  Op[ks][b][q][h] = sum over this block's k-tiles of
// (exp(s)*inv_d) @ V.  grid = (64 q-tiles, 2 k-splits, B).
// ---------------------------------------------------------------------------
__global__ __launch_bounds__(256) void out_kernel(
    const float* __restrict__ Qw, const float* __restrict__ Kw,
    const float* __restrict__ Vw, const float* __restrict__ Dp,
    float* __restrict__ Op)
{
    __shared__ float qsT[CHEAD][LDSP];  // [h][q]
    __shared__ float ksT[CHEAD][LDSP];  // [h][k]
    __shared__ float vsm[TILE][LDSP];   // [k][h]
    __shared__ float psT[TILE][LDSP];   // [k][q]
    __shared__ float idcol[TILE];
    const int qt = blockIdx.x;
    const int ks = blockIdx.y;
    const int b  = blockIdx.z;
    const int q0 = qt * TILE;
    const float* Qb = Qw + (size_t)b * T_SEQ * CHEAD;
    const float* Kb = Kw + (size_t)b * T_SEQ * CHEAD;
    const float* Vb = Vw + (size_t)b * T_SEQ * CHEAD;
    const int tid = threadIdx.x;
    const int tx = tid & 15, ty = tid >> 4;

    #pragma unroll
    for (int l = 0; l < 4; ++l) {                  // Q tile once, transposed
        int idx = tid + l * 256;
        int r  = idx >> 4;
        int h4 = (idx & 15) << 2;
        float4 v = *reinterpret_cast<const float4*>(
            Qb + (size_t)(q0 + r) * CHEAD + h4);
        qsT[h4 + 0][r] = v.x; qsT[h4 + 1][r] = v.y;
        qsT[h4 + 2][r] = v.z; qsT[h4 + 3][r] = v.w;
    }
    float acc[4][4] = {};
    __syncthreads();

    for (int kt = ks; kt <= qt; kt += 2) {
        const int k0 = kt * TILE;
        #pragma unroll
        for (int l = 0; l < 4; ++l) {              // K (transposed) + V (direct)
            int idx = tid + l * 256;
            int r  = idx >> 4;
            int h4 = (idx & 15) << 2;
            float4 v = *reinterpret_cast<const float4*>(
                Kb + (size_t)(k0 + r) * CHEAD + h4);
            ksT[h4 + 0][r] = v.x; ksT[h4 + 1][r] = v.y;
            ksT[h4 + 2][r] = v.z; ksT[h4 + 3][r] = v.w;
            float4 vv = *reinterpret_cast<const float4*>(
                Vb + (size_t)(k0 + r) * CHEAD + h4);
            *reinterpret_cast<float4*>(&vsm[r][h4]) = vv;
        }
        if (tid < 64) {                            // combine 4 denom partials
            size_t base = (size_t)b * T_SEQ + k0 + tid;
            const size_t S = (size_t)NBATCH * T_SEQ;
            float d = Dp[base] + Dp[S + base] + Dp[2 * S + base] + Dp[3 * S + base];
            idcol[tid] = 1.0f / d;
        }
        __syncthreads();

        float s[4][4] = {};
        #pragma unroll 8
        for (int h = 0; h < CHEAD; ++h) {
            float4 a  = *reinterpret_cast<const float4*>(&qsT[h][ty << 2]);
            float4 bb = *reinterpret_cast<const float4*>(&ksT[h][tx << 2]);
            float av[4] = {a.x, a.y, a.z, a.w};
            float bv[4] = {bb.x, bb.y, bb.z, bb.w};
            #pragma unroll
            for (int i = 0; i < 4; ++i)
                #pragma unroll
                for (int j = 0; j < 4; ++j)
                    s[i][j] = fmaf(av[i], bv[j], s[i][j]);
        }
        #pragma unroll
        for (int j = 0; j < 4; ++j) {              // p = exp(s/8) * inv_d
            int kcol = k0 + (tx << 2) + j;
            float invd = idcol[(tx << 2) + j];
            float pv[4];
            #pragma unroll
            for (int i = 0; i < 4; ++i) {
                int q = q0 + (ty << 2) + i;
                pv[i] = (q >= kcol) ? __expf(s[i][j] * 0.125f) * invd : 0.f;
            }
            *reinterpret_cast<float4*>(&psT[(tx << 2) + j][ty << 2]) =
                make_float4(pv[0], pv[1], pv[2], pv[3]);
        }
        __syncthreads();
        #pragma unroll 8
        for (int kk = 0; kk < TILE; ++kk) {        // acc += P^T row * V row
            float4 a = *reinterpret_cast<const float4*>(&psT[kk][ty << 2]);
            float4 v = *reinterpret_cast<const float4*>(&vsm[kk][tx << 2]);
            float av[4] = {a.x, a.y, a.z, a.w};
            float vv[4] = {v.x, v.y, v.z, v.w};
            #pragma unroll
            for (int i = 0; i < 4; ++i)
                #pragma unroll
                for (int j = 0; j < 4; ++j)
                    acc[i][j] = fmaf(av[i], vv[j], acc[i][j]);
        }
        __syncthreads();
    }
    float* Ob = Op + ((size_t)ks * NBATCH + b) * T_SEQ * CHEAD;
    #pragma unroll
    for (int i = 0; i < 4; ++i) {
        float4 o = make_float4(acc[i][0], acc[i][1], acc[i][2], acc[i][3]);
        *reinterpret_cast<float4*>(
            Ob + (size_t)(q0 + (ty << 2) + i) * CHEAD + (tx << 2)) = o;
    }
}

// ---------------------------------------------------------------------------
// Kernel 4: out = Op[0] + Op[1]   (deterministic k-split combine)
// ---------------------------------------------------------------------------
__global__ __launch_bounds__(256) void combine_kernel(
    const float* __restrict__ Op, float* __restrict__ out)
{
    const size_t N = (size_t)NBATCH * T_SEQ * CHEAD;
    size_t i = ((size_t)blockIdx.x * 256 + threadIdx.x) * 4;
    float4 a = *reinterpret_cast<const float4*>(Op + i);
    float4 b = *reinterpret_cast<const float4*>(Op + N + i);
    *reinterpret_cast<float4*>(out + i) =
        make_float4(a.x + b.x, a.y + b.y, a.z + b.z, a.w + b.w);
}

extern "C" void kernel_launch(void* const* d_in, const int* in_sizes, int n_in,
                              void* d_out, int out_size, void* d_ws, size_t ws_size,
                              hipStream_t stream) {
    (void)in_sizes; (void)n_in; (void)out_size; (void)ws_size;
    const float* x  = (const float*)d_in[0];
    const float* Wk = (const float*)d_in[1];
    const float* Wq = (const float*)d_in[2];
    const float* Wv = (const float*)d_in[3];
    float* out = (float*)d_out;
    float* ws  = (float*)d_ws;

    const size_t BTH = (size_t)NBATCH * T_SEQ * CHEAD;   // 2,097,152
    float* Qw = ws;
    float* Kw = ws + BTH;
    float* Vw = ws + 2 * BTH;
    float* Dp = ws + 3 * BTH;                             // [4][B*T]
    float* Op = Dp + 4 * (size_t)NBATCH * T_SEQ;          // [2][B*T*64]
    // total ws use: 3*BTH + 131072 + 2*BTH floats ≈ 42.5 MB

    hipLaunchKernelGGL(proj_kernel,   dim3(512, 3),        dim3(256), 0, stream,
                       x, Wk, Wq, Wv, Qw, Kw, Vw);
    hipLaunchKernelGGL(colsum_kernel, dim3(64, 4, NBATCH), dim3(256), 0, stream,
                       Qw, Kw, Dp);
    hipLaunchKernelGGL(out_kernel,    dim3(64, 2, NBATCH), dim3(256), 0, stream,
                       Qw, Kw, Vw, Dp, Op);
    hipLaunchKernelGGL(combine_kernel, dim3(2048),         dim3(256), 0, stream,
                       Op, out);
}

// Round 2
// 513.765 us; speedup vs baseline: 1.9540x; 1.9540x over previous
//
#include <hip/hip_runtime.h>
#include <math.h>

#define T_SEQ 4096
#define CEMB  1024
#define CHEAD 64
#define NB    8

typedef __attribute__((ext_vector_type(8))) short bf8;   // 8 bf16 (4 VGPRs)
typedef __attribute__((ext_vector_type(4))) short s4v;   // 4 bf16 (8B)
typedef __attribute__((ext_vector_type(4))) float f4;    // MFMA C/D

#define MFMA(a, b, c) __builtin_amdgcn_mfma_f32_16x16x32_bf16((a), (b), (c), 0, 0, 0)

__device__ __forceinline__ short f2bf(float f) {
    unsigned int u = __float_as_uint(f);
    u += 0x7fffu + ((u >> 16) & 1u);          // round-to-nearest-even
    return (short)(u >> 16);
}
__device__ __forceinline__ float bf2f(short h) {
    return __uint_as_float(((unsigned int)(unsigned short)h) << 16);
}

// ---------------------------------------------------------------------------
// Kernel 0: W -> transposed hi/lo bf16 split.  Wt[m][h][c], m: 0=Q 1=K 2=V
// ---------------------------------------------------------------------------
__global__ __launch_bounds__(256) void wsplit_kernel(
    const float* __restrict__ Wk, const float* __restrict__ Wq,
    const float* __restrict__ Wv,
    short* __restrict__ Wthi, short* __restrict__ Wtlo)
{
    int id = blockIdx.x * 256 + threadIdx.x;       // exactly 3*65536 threads
    int m = id >> 16;
    int rem = id & 65535;
    int c = rem >> 6, h = rem & 63;
    const float* W = (m == 0) ? Wq : (m == 1) ? Wk : Wv;
    float f = W[c * 64 + h];
    short hi = f2bf(f);
    short lo = f2bf(f - bf2f(hi));
    Wthi[m * 65536 + h * 1024 + c] = hi;
    Wtlo[m * 65536 + h * 1024 + c] = lo;
}

// ---------------------------------------------------------------------------
// Kernel 1: QKV projection via split-3 bf16 MFMA.
// Outputs: Qhi/Qlo, Khi/Klo row-major [B*T][64]; VThi/VTlo transposed [B][64][T].
// grid 256 blocks (128-row tiles), 256 thr (4 waves x 32 rows).
// ---------------------------------------------------------------------------
__global__ __launch_bounds__(256) void proj_kernel(
    const float* __restrict__ x,
    const short* __restrict__ Wthi, const short* __restrict__ Wtlo,
    short* __restrict__ Qhi, short* __restrict__ Qlo,
    short* __restrict__ Khi, short* __restrict__ Klo,
    short* __restrict__ VThi, short* __restrict__ VTlo)
{
    __shared__ short xs[2][128][72];   // hi/lo x tile  (36.9 KB)
    __shared__ short wt[6][64][72];    // 3 matrices x hi/lo, transposed (55.3 KB)
    const int tid = threadIdx.x;
    const int lane = tid & 63, w = tid >> 6;
    const int l15 = lane & 15, lg = lane >> 4;
    const int row0 = blockIdx.x * 128;

    f4 acc[3][2][4] = {};

    for (int c0 = 0; c0 < CEMB; c0 += 64) {
        __syncthreads();
        #pragma unroll
        for (int l = 0; l < 8; ++l) {             // x tile 128x64 fp32 -> hi/lo
            int id = tid + l * 256;
            int r = id >> 4, col = (id & 15) << 2;
            float4 v = *reinterpret_cast<const float4*>(
                x + (size_t)(row0 + r) * CEMB + c0 + col);
            float fv[4] = {v.x, v.y, v.z, v.w};
            s4v hi, lo;
            #pragma unroll
            for (int e = 0; e < 4; ++e) {
                hi[e] = f2bf(fv[e]);
                lo[e] = f2bf(fv[e] - bf2f(hi[e]));
            }
            *reinterpret_cast<s4v*>(&xs[0][r][col]) = hi;
            *reinterpret_cast<s4v*>(&xs[1][r][col]) = lo;
        }
        #pragma unroll
        for (int l = 0; l < 12; ++l) {            // Wt tiles 6 x 64 x 64 bf16
            int id = tid + l * 256;               // [0, 3072)
            int t6 = id >> 9;
            int rem = id & 511;
            int r = rem >> 3, c8 = (rem & 7) << 3;
            int m = t6 >> 1, hl = t6 & 1;
            const short* src = (hl ? Wtlo : Wthi) + m * 65536 + r * 1024 + c0 + c8;
            *reinterpret_cast<bf8*>(&wt[t6][r][c8]) =
                *reinterpret_cast<const bf8*>(src);
        }
        __syncthreads();

        bf8 xa_hi[2][2], xa_lo[2][2];
        #pragma unroll
        for (int qf = 0; qf < 2; ++qf)
            #pragma unroll
            for (int dc = 0; dc < 2; ++dc) {
                xa_hi[qf][dc] = *reinterpret_cast<const bf8*>(
                    &xs[0][w * 32 + 16 * qf + l15][dc * 32 + lg * 8]);
                xa_lo[qf][dc] = *reinterpret_cast<const bf8*>(
                    &xs[1][w * 32 + 16 * qf + l15][dc * 32 + lg * 8]);
            }
        #pragma unroll
        for (int m = 0; m < 3; ++m)
            #pragma unroll
            for (int dc = 0; dc < 2; ++dc) {
                bf8 wbh[4], wbl[4];
                #pragma unroll
                for (int hf = 0; hf < 4; ++hf) {
                    wbh[hf] = *reinterpret_cast<const bf8*>(
                        &wt[2 * m][16 * hf + l15][dc * 32 + lg * 8]);
                    wbl[hf] = *reinterpret_cast<const bf8*>(
                        &wt[2 * m + 1][16 * hf + l15][dc * 32 + lg * 8]);
                }
                #pragma unroll
                for (int qf = 0; qf < 2; ++qf)
                    #pragma unroll
                    for (int hf = 0; hf < 4; ++hf) {
                        acc[m][qf][hf] = MFMA(xa_hi[qf][dc], wbh[hf], acc[m][qf][hf]);
                        acc[m][qf][hf] = MFMA(xa_hi[qf][dc], wbl[hf], acc[m][qf][hf]);
                        acc[m][qf][hf] = MFMA(xa_lo[qf][dc], wbh[hf], acc[m][qf][hf]);
                    }
            }
    }
    // epilogue: split results to bf16 hi/lo and store
    #pragma unroll
    for (int qf = 0; qf < 2; ++qf)
        #pragma unroll
        for (int hf = 0; hf < 4; ++hf) {
            int hcol = 16 * hf + l15;
            int qb = row0 + w * 32 + 16 * qf + lg * 4;    // + r
            #pragma unroll
            for (int r = 0; r < 4; ++r) {
                float fq = acc[0][qf][hf][r];
                short hq = f2bf(fq);
                Qhi[(size_t)(qb + r) * 64 + hcol] = hq;
                Qlo[(size_t)(qb + r) * 64 + hcol] = f2bf(fq - bf2f(hq));
                float fk = acc[1][qf][hf][r];
                short hk = f2bf(fk);
                Khi[(size_t)(qb + r) * 64 + hcol] = hk;
                Klo[(size_t)(qb + r) * 64 + hcol] = f2bf(fk - bf2f(hk));
            }
            int bb = qb >> 12, t0 = qb & 4095;            // 128 | 4096: no spanning
            s4v vh, vl;
            #pragma unroll
            for (int r = 0; r < 4; ++r) {
                float fv = acc[2][qf][hf][r];
                vh[r] = f2bf(fv);
                vl[r] = f2bf(fv - bf2f(vh[r]));
            }
            *reinterpret_cast<s4v*>(&VThi[((size_t)bb * 64 + hcol) * T_SEQ + t0]) = vh;
            *reinterpret_cast<s4v*>(&VTlo[((size_t)bb * 64 + hcol) * T_SEQ + t0]) = vl;
        }
}

// ---------------------------------------------------------------------------
// Kernel 2: column denominators d_k = sum_{q>=k} exp(s*0.125) via MFMA.
// grid (64 k-tiles, 4 q-splits, B); K-frags register-resident; Q direct loads.
// ---------------------------------------------------------------------------
__global__ __launch_bounds__(256, 2) void colsum_kernel(
    const short* __restrict__ Qhi, const short* __restrict__ Qlo,
    const short* __restrict__ Khi, const short* __restrict__ Klo,
    float* __restrict__ Dp)
{
    __shared__ float red[4][64];
    const int tid = threadIdx.x;
    const int lane = tid & 63, w = tid >> 6;
    const int l15 = lane & 15, lg = lane >> 4;
    const int k0 = blockIdx.x * 64;
    const int qs = blockIdx.y, b = blockIdx.z;
    const size_t bT = (size_t)b * T_SEQ;

    bf8 kbh[4][2], kbl[4][2];
    #pragma unroll
    for (int kf = 0; kf < 4; ++kf)
        #pragma unroll
        for (int dc = 0; dc < 2; ++dc) {
            size_t o = (bT + k0 + 16 * kf + l15) * 64 + dc * 32 + lg * 8;
            kbh[kf][dc] = *reinterpret_cast<const bf8*>(Khi + o);
            kbl[kf][dc] = *reinterpret_cast<const bf8*>(Klo + o);
        }
    float csum[4] = {0.f, 0.f, 0.f, 0.f};

    for (int q0 = k0 + qs * 128; q0 < T_SEQ; q0 += 512) {
        bf8 qah[2][2], qal[2][2];
        #pragma unroll
        for (int qf = 0; qf < 2; ++qf)
            #pragma unroll
            for (int dc = 0; dc < 2; ++dc) {
                int row = q0 + w * 32 + 16 * qf + l15;
                row = row < T_SEQ ? row : T_SEQ - 1;      // clamp; masked below
                size_t o = (bT + row) * 64 + dc * 32 + lg * 8;
                qah[qf][dc] = *reinterpret_cast<const bf8*>(Qhi + o);
                qal[qf][dc] = *reinterpret_cast<const bf8*>(Qlo + o);
            }
        f4 s[2][4] = {};
        #pragma unroll
        for (int dc = 0; dc < 2; ++dc)
            #pragma unroll
            for (int qf = 0; qf < 2; ++qf)
                #pragma unroll
                for (int kf = 0; kf < 4; ++kf) {
                    s[qf][kf] = MFMA(qah[qf][dc], kbh[kf][dc], s[qf][kf]);
                    s[qf][kf] = MFMA(qah[qf][dc], kbl[kf][dc], s[qf][kf]);
                    s[qf][kf] = MFMA(qal[qf][dc], kbh[kf][dc], s[qf][kf]);
                }
        #pragma unroll
        for (int qf = 0; qf < 2; ++qf)
            #pragma unroll
            for (int kf = 0; kf < 4; ++kf)
                #pragma unroll
                for (int r = 0; r < 4; ++r) {
                    int q = q0 + w * 32 + 16 * qf + lg * 4 + r;
                    int kc = k0 + 16 * kf + l15;
                    if (q >= kc && q < T_SEQ)
                        csum[kf] += __expf(s[qf][kf][r] * 0.125f);
                }
    }
    #pragma unroll
    for (int kf = 0; kf < 4; ++kf) {                      // reduce lane groups
        csum[kf] += __shfl_xor(csum[kf], 16);
        csum[kf] += __shfl_xor(csum[kf], 32);
    }
    if (lg == 0) {
        #pragma unroll
        for (int kf = 0; kf < 4; ++kf) red[w][16 * kf + l15] = csum[kf];
    }
    __syncthreads();
    if (tid < 64) {
        float d = red[0][tid] + red[1][tid] + red[2][tid] + red[3][tid];
        Dp[((size_t)qs * NB + b) * T_SEQ + k0 + tid] = d;
    }
}

// ---------------------------------------------------------------------------
// Kernel 3: O = (exp(S)/d) @ V via MFMA (split-3 for both S and PV).
// grid 512: half=bx>>8, qt = half ? 31-i : i, ks-interleaved k-split.
// Pairing makes co-resident block pairs sum to uniform 33 k-chunks.
// half 0 -> d_out, half 1 -> Op1; combine adds.
// ---------------------------------------------------------------------------
__global__ __launch_bounds__(256, 2) void out_kernel(
    const short* __restrict__ Qhi, const short* __restrict__ Qlo,
    const short* __restrict__ Khi, const short* __restrict__ Klo,
    const short* __restrict__ VThi, const short* __restrict__ VTlo,
    const float* __restrict__ Dp,
    float* __restrict__ out, float* __restrict__ Op1)
{
    __shared__ short kv[4][64][72];     // Khi,Klo,VThi,VTlo tiles (36.9 KB)
    __shared__ short Pt[2][128][72];    // P hi/lo, per-wave-private rows (36.9 KB)
    __shared__ float idcol[64];
    const int tid = threadIdx.x;
    const int lane = tid & 63, w = tid >> 6;
    const int l15 = lane & 15, lg = lane >> 4;
    const int bx = blockIdx.x;
    const int half = bx >> 8;
    const int j = bx & 255;
    const int b = j >> 5;
    const int i = j & 31;
    const int qt = half ? 31 - i : i;
    const int q0 = qt * 128;
    const size_t bT = (size_t)b * T_SEQ;

    bf8 qah[2][2], qal[2][2];           // persistent Q fragments
    #pragma unroll
    for (int qf = 0; qf < 2; ++qf)
        #pragma unroll
        for (int dc = 0; dc < 2; ++dc) {
            size_t o = (bT + q0 + w * 32 + 16 * qf + l15) * 64 + dc * 32 + lg * 8;
            qah[qf][dc] = *reinterpret_cast<const bf8*>(Qhi + o);
            qal[qf][dc] = *reinterpret_cast<const bf8*>(Qlo + o);
        }
    f4 oacc[2][4] = {};

    for (int k0 = half * 64; k0 < q0 + 128; k0 += 128) {
        __syncthreads();                               // protect K/V reuse
        #pragma unroll
        for (int l = 0; l < 8; ++l) {                  // stage K hi/lo + VT hi/lo
            int id = tid + l * 256;
            int tile = id >> 9, rem = id & 511;
            int r = rem >> 3, c8 = (rem & 7) << 3;
            const short* src;
            if (tile == 0)      src = Khi  + (bT + k0 + r) * 64 + c8;
            else if (tile == 1) src = Klo  + (bT + k0 + r) * 64 + c8;
            else if (tile == 2) src = VThi + ((size_t)b * 64 + r) * T_SEQ + k0 + c8;
            else                src = VTlo + ((size_t)b * 64 + r) * T_SEQ + k0 + c8;
            *reinterpret_cast<bf8*>(&kv[tile][r][c8]) =
                *reinterpret_cast<const bf8*>(src);
        }
        if (tid < 64) {                                // combine denom partials
            int kk = k0 + tid;
            float d = Dp[((size_t)0 * NB + b) * T_SEQ + kk]
                    + Dp[((size_t)1 * NB + b) * T_SEQ + kk]
                    + Dp[((size_t)2 * NB + b) * T_SEQ + kk]
                    + Dp[((size_t)3 * NB + b) * T_SEQ + kk];
            idcol[tid] = 1.0f / d;
        }
        __syncthreads();

        f4 s[2][4] = {};
        #pragma unroll
        for (int dc = 0; dc < 2; ++dc) {
            bf8 kbh[4], kbl[4];
            #pragma unroll
            for (int kf = 0; kf < 4; ++kf) {
                kbh[kf] = *reinterpret_cast<const bf8*>(&kv[0][16 * kf + l15][dc * 32 + lg * 8]);
                kbl[kf] = *reinterpret_cast<const bf8*>(&kv[1][16 * kf + l15][dc * 32 + lg * 8]);
            }
            #pragma unroll
            for (int qf = 0; qf < 2; ++qf)
                #pragma unroll
                for (int kf = 0; kf < 4; ++kf) {
                    s[qf][kf] = MFMA(qah[qf][dc], kbh[kf], s[qf][kf]);
                    s[qf][kf] = MFMA(qah[qf][dc], kbl[kf], s[qf][kf]);
                    s[qf][kf] = MFMA(qal[qf][dc], kbh[kf], s[qf][kf]);
                }
        }
        float invd[4];
        #pragma unroll
        for (int kf = 0; kf < 4; ++kf) invd[kf] = idcol[16 * kf + l15];
        #pragma unroll
        for (int qf = 0; qf < 2; ++qf)
            #pragma unroll
            for (int kf = 0; kf < 4; ++kf)
                #pragma unroll
                for (int r = 0; r < 4; ++r) {
                    int q  = q0 + w * 32 + 16 * qf + lg * 4 + r;
                    int kc = k0 + 16 * kf + l15;
                    float p = (q >= kc) ? __expf(s[qf][kf][r] * 0.125f) * invd[kf] : 0.f;
                    short ph = f2bf(p);
                    short pl = f2bf(p - bf2f(ph));
                    Pt[0][w * 32 + 16 * qf + lg * 4 + r][16 * kf + l15] = ph;
                    Pt[1][w * 32 + 16 * qf + lg * 4 + r][16 * kf + l15] = pl;
                }
        // PV: O += P @ V  (split-3); P rows are this wave's own -> no barrier
        #pragma unroll
        for (int kc2 = 0; kc2 < 2; ++kc2) {
            bf8 vbh[4], vbl[4];
            #pragma unroll
            for (int hf = 0; hf < 4; ++hf) {
                vbh[hf] = *reinterpret_cast<const bf8*>(&kv[2][16 * hf + l15][kc2 * 32 + lg * 8]);
                vbl[hf] = *reinterpret_cast<const bf8*>(&kv[3][16 * hf + l15][kc2 * 32 + lg * 8]);
            }
            #pragma unroll
            for (int qf = 0; qf < 2; ++qf) {
                bf8 pah = *reinterpret_cast<const bf8*>(&Pt[0][w * 32 + 16 * qf + l15][kc2 * 32 + lg * 8]);
                bf8 pal = *reinterpret_cast<const bf8*>(&Pt[1][w * 32 + 16 * qf + l15][kc2 * 32 + lg * 8]);
                #pragma unroll
                for (int hf = 0; hf < 4; ++hf) {
                    oacc[qf][hf] = MFMA(pah, vbh[hf], oacc[qf][hf]);
                    oacc[qf][hf] = MFMA(pah, vbl[hf], oacc[qf][hf]);
                    oacc[qf][hf] = MFMA(pal, vbh[hf], oacc[qf][hf]);
                }
            }
        }
    }
    float* dst = half ? Op1 : out;
    #pragma unroll
    for (int qf = 0; qf < 2; ++qf)
        #pragma unroll
        for (int hf = 0; hf < 4; ++hf)
            #pragma unroll
            for (int r = 0; r < 4; ++r) {
                int q = q0 + w * 32 + 16 * qf + lg * 4 + r;
                dst[(bT + q) * 64 + 16 * hf + l15] = oacc[qf][hf][r];
            }
}

// ---------------------------------------------------------------------------
// Kernel 4: out += Op1 (deterministic k-split combine)
// ---------------------------------------------------------------------------
__global__ __launch_bounds__(256) void combine_kernel(
    float* __restrict__ out, const float* __restrict__ Op1)
{
    size_t idx = ((size_t)blockIdx.x * 256 + threadIdx.x) * 4;
    float4 a = *reinterpret_cast<const float4*>(out + idx);
    float4 c = *reinterpret_cast<const float4*>(Op1 + idx);
    *reinterpret_cast<float4*>(out + idx) =
        make_float4(a.x + c.x, a.y + c.y, a.z + c.z, a.w + c.w);
}

extern "C" void kernel_launch(void* const* d_in, const int* in_sizes, int n_in,
                              void* d_out, int out_size, void* d_ws, size_t ws_size,
                              hipStream_t stream) {
    (void)in_sizes; (void)n_in; (void)out_size; (void)ws_size;
    const float* x  = (const float*)d_in[0];
    const float* Wk = (const float*)d_in[1];
    const float* Wq = (const float*)d_in[2];
    const float* Wv = (const float*)d_in[3];
    float* out = (float*)d_out;
    char* w8 = (char*)d_ws;

    const size_t SZ = (size_t)NB * T_SEQ * CHEAD * sizeof(short);  // 4,194,304
    short* Qhi  = (short*)(w8);
    short* Qlo  = (short*)(w8 + SZ);
    short* Khi  = (short*)(w8 + 2 * SZ);
    short* Klo  = (short*)(w8 + 3 * SZ);
    short* VThi = (short*)(w8 + 4 * SZ);
    short* VTlo = (short*)(w8 + 5 * SZ);
    short* Wthi = (short*)(w8 + 6 * SZ);                  // 393,216 B
    short* Wtlo = (short*)(w8 + 6 * SZ + 393216);
    float* Dp   = (float*)(w8 + 6 * SZ + 786432);         // 524,288 B
    float* Op1  = (float*)(w8 + 6 * SZ + 786432 + 524288);
    // total ws use ≈ 34.9 MB (round-1 footprint was 42.5 MB, so within budget)

    hipLaunchKernelGGL(wsplit_kernel, dim3(768), dim3(256), 0, stream,
                       Wk, Wq, Wv, Wthi, Wtlo);
    hipLaunchKernelGGL(proj_kernel, dim3(256), dim3(256), 0, stream,
                       x, Wthi, Wtlo, Qhi, Qlo, Khi, Klo, VThi, VTlo);
    hipLaunchKernelGGL(colsum_kernel, dim3(64, 4, NB), dim3(256), 0, stream,
                       Qhi, Qlo, Khi, Klo, Dp);
    hipLaunchKernelGGL(out_kernel, dim3(512), dim3(256), 0, stream,
                       Qhi, Qlo, Khi, Klo, VThi, VTlo, Dp, out, Op1);
    hipLaunchKernelGGL(combine_kernel, dim3(2048), dim3(256), 0, stream,
                       out, Op1);
}

// Round 4
// 455.297 us; speedup vs baseline: 2.2050x; 1.1284x over previous
//
#include <hip/hip_runtime.h>
#include <math.h>

#define T_SEQ 4096
#define CEMB  1024
#define CHEAD 64
#define NB    8

typedef __attribute__((ext_vector_type(8))) short bf8;   // 8 bf16 (4 VGPRs)
typedef __attribute__((ext_vector_type(4))) short s4v;   // 4 bf16 (8B)
typedef __attribute__((ext_vector_type(4))) float f4;    // MFMA C/D

#define MFMA(a, b, c) __builtin_amdgcn_mfma_f32_16x16x32_bf16((a), (b), (c), 0, 0, 0)

__device__ __forceinline__ short f2bf(float f) {
    unsigned int u = __float_as_uint(f);
    u += 0x7fffu + ((u >> 16) & 1u);          // round-to-nearest-even
    return (short)(u >> 16);
}
__device__ __forceinline__ float bf2f(short h) {
    return __uint_as_float(((unsigned int)(unsigned short)h) << 16);
}

// ---------------------------------------------------------------------------
// Kernel 0: W -> hi/lo bf16 split in a chunk-major, XOR-swizzled layout:
// Wp[c>>5][2m+hl][h][ (c&31) ^ (((h>>1)&3)<<3) ]   (shorts)
// ---------------------------------------------------------------------------
__global__ __launch_bounds__(256) void wsplit_kernel(
    const float* __restrict__ Wk, const float* __restrict__ Wq,
    const float* __restrict__ Wv, short* __restrict__ Wp)
{
    int id = blockIdx.x * 256 + threadIdx.x;       // exactly 3*65536 threads
    int m = id >> 16;
    int rem = id & 65535;
    int c = rem >> 6, h = rem & 63;
    const float* W = (m == 0) ? Wq : (m == 1) ? Wk : Wv;
    float f = W[c * 64 + h];
    short hi = f2bf(f);
    short lo = f2bf(f - bf2f(hi));
    int cs = (c & 31) ^ (((h >> 1) & 3) << 3);
    size_t base = ((size_t)(c >> 5) * 6) * 2048 + (size_t)h * 32 + cs;
    Wp[base + (size_t)(2 * m) * 2048]     = hi;
    Wp[base + (size_t)(2 * m + 1) * 2048] = lo;
}

// ---------------------------------------------------------------------------
// Kernel 1: QKV projection.  x A-frags direct global->reg (hi/lo split in
// registers); W via double-buffered global_load_lds chunks (KC=32).
// grid 512 x 128thr (2 waves x 32 rows); LDS 48KB -> 2 blocks/CU.
// ---------------------------------------------------------------------------
__global__ __launch_bounds__(128) void proj_kernel(
    const float* __restrict__ x, const short* __restrict__ Wp,
    short* __restrict__ Qhi, short* __restrict__ Qlo,
    short* __restrict__ Khi, short* __restrict__ Klo,
    short* __restrict__ VThi, short* __restrict__ VTlo)
{
    __shared__ short wbuf[2][12288];               // 2 x 24KB
    const int tid = threadIdx.x;
    const int lane = tid & 63, w = tid >> 6;       // w in 0..1
    const int l15 = lane & 15, lg = lane >> 4;
    const int row0 = blockIdx.x * 64;

    f4 acc[3][2][4] = {};
    float4 xrawA[2][2], xrawB[2][2];

    auto stage = [&](int c, int buf) {
        const short* src = Wp + (size_t)c * 12288 + w * 6144 + lane * 8;
        #pragma unroll
        for (int p = 0; p < 12; ++p) {
            __builtin_amdgcn_global_load_lds(
                (const __attribute__((address_space(1))) void*)(src + p * 512),
                (__attribute__((address_space(3))) void*)&wbuf[buf][w * 6144 + p * 512],
                16, 0, 0);
        }
    };
    auto xload = [&](int c, float4 (&xr)[2][2]) {
        #pragma unroll
        for (int qf = 0; qf < 2; ++qf) {
            const float* px = x + (size_t)(row0 + 32 * w + 16 * qf + l15) * CEMB
                                + c * 32 + lg * 8;
            xr[qf][0] = *reinterpret_cast<const float4*>(px);
            xr[qf][1] = *reinterpret_cast<const float4*>(px + 4);
        }
    };
    const int swz = ((l15 >> 1) & 3) << 3;         // (h>>1)&3 == (l15>>1)&3
    auto compute = [&](const float4 (&xr)[2][2], int buf) {
        bf8 xh[2], xl[2];
        #pragma unroll
        for (int qf = 0; qf < 2; ++qf) {
            #pragma unroll
            for (int hv = 0; hv < 2; ++hv) {
                const float* fp = reinterpret_cast<const float*>(&xr[qf][hv]);
                #pragma unroll
                for (int e = 0; e < 4; ++e) {
                    float f = fp[e];
                    short hb = f2bf(f);
                    xh[qf][hv * 4 + e] = hb;
                    xl[qf][hv * 4 + e] = f2bf(f - bf2f(hb));
                }
            }
        }
        #pragma unroll
        for (int m = 0; m < 3; ++m) {
            #pragma unroll
            for (int hf = 0; hf < 4; ++hf) {
                int h = 16 * hf + l15;
                const short* bp = &wbuf[buf][(2 * m) * 2048 + h * 32 + ((lg << 3) ^ swz)];
                bf8 wh = *reinterpret_cast<const bf8*>(bp);
                bf8 wl = *reinterpret_cast<const bf8*>(bp + 2048);
                #pragma unroll
                for (int qf = 0; qf < 2; ++qf) {
                    acc[m][qf][hf] = MFMA(xh[qf], wh, acc[m][qf][hf]);
                    acc[m][qf][hf] = MFMA(xh[qf], wl, acc[m][qf][hf]);
                    acc[m][qf][hf] = MFMA(xl[qf], wh, acc[m][qf][hf]);
                }
            }
        }
    };

    stage(0, 0);
    xload(0, xrawA);
    __syncthreads();
    for (int c = 0; c < 32; c += 2) {
        stage(c + 1, 1);                            // c+1 <= 31 always
        xload(c + 1, xrawB);
        compute(xrawA, 0);
        __syncthreads();
        if (c + 2 < 32) { stage(c + 2, 0); xload(c + 2, xrawA); }
        compute(xrawB, 1);
        __syncthreads();
    }

    // epilogue: split results to bf16 hi/lo and store
    #pragma unroll
    for (int qf = 0; qf < 2; ++qf)
        #pragma unroll
        for (int hf = 0; hf < 4; ++hf) {
            int hcol = 16 * hf + l15;
            int qb = row0 + 32 * w + 16 * qf + lg * 4;    // + r
            #pragma unroll
            for (int r = 0; r < 4; ++r) {
                float fq = acc[0][qf][hf][r];
                short hq = f2bf(fq);
                Qhi[(size_t)(qb + r) * 64 + hcol] = hq;
                Qlo[(size_t)(qb + r) * 64 + hcol] = f2bf(fq - bf2f(hq));
                float fk = acc[1][qf][hf][r];
                short hk = f2bf(fk);
                Khi[(size_t)(qb + r) * 64 + hcol] = hk;
                Klo[(size_t)(qb + r) * 64 + hcol] = f2bf(fk - bf2f(hk));
            }
            int bb = qb >> 12, t0 = qb & 4095;            // 64 | 4096: no spanning
            s4v vh, vl;
            #pragma unroll
            for (int r = 0; r < 4; ++r) {
                float fv = acc[2][qf][hf][r];
                vh[r] = f2bf(fv);
                vl[r] = f2bf(fv - bf2f(vh[r]));
            }
            *reinterpret_cast<s4v*>(&VThi[((size_t)bb * 64 + hcol) * T_SEQ + t0]) = vh;
            *reinterpret_cast<s4v*>(&VTlo[((size_t)bb * 64 + hcol) * T_SEQ + t0]) = vl;
        }
}

// ---------------------------------------------------------------------------
// Kernel 2: column denominators d_k = sum_{q>=k} exp(s*0.125) via MFMA.
// ---------------------------------------------------------------------------
__global__ __launch_bounds__(256, 2) void colsum_kernel(
    const short* __restrict__ Qhi, const short* __restrict__ Qlo,
    const short* __restrict__ Khi, const short* __restrict__ Klo,
    float* __restrict__ Dp)
{
    __shared__ float red[4][64];
    const int tid = threadIdx.x;
    const int lane = tid & 63, w = tid >> 6;
    const int l15 = lane & 15, lg = lane >> 4;
    const int k0 = blockIdx.x * 64;
    const int qs = blockIdx.y, b = blockIdx.z;
    const size_t bT = (size_t)b * T_SEQ;

    bf8 kbh[4][2], kbl[4][2];
    #pragma unroll
    for (int kf = 0; kf < 4; ++kf)
        #pragma unroll
        for (int dc = 0; dc < 2; ++dc) {
            size_t o = (bT + k0 + 16 * kf + l15) * 64 + dc * 32 + lg * 8;
            kbh[kf][dc] = *reinterpret_cast<const bf8*>(Khi + o);
            kbl[kf][dc] = *reinterpret_cast<const bf8*>(Klo + o);
        }
    float csum[4] = {0.f, 0.f, 0.f, 0.f};

    for (int q0 = k0 + qs * 128; q0 < T_SEQ; q0 += 512) {
        bf8 qah[2][2], qal[2][2];
        #pragma unroll
        for (int qf = 0; qf < 2; ++qf)
            #pragma unroll
            for (int dc = 0; dc < 2; ++dc) {
                int row = q0 + w * 32 + 16 * qf + l15;
                row = row < T_SEQ ? row : T_SEQ - 1;      // clamp; masked below
                size_t o = (bT + row) * 64 + dc * 32 + lg * 8;
                qah[qf][dc] = *reinterpret_cast<const bf8*>(Qhi + o);
                qal[qf][dc] = *reinterpret_cast<const bf8*>(Qlo + o);
            }
        f4 s[2][4] = {};
        #pragma unroll
        for (int dc = 0; dc < 2; ++dc)
            #pragma unroll
            for (int qf = 0; qf < 2; ++qf)
                #pragma unroll
                for (int kf = 0; kf < 4; ++kf) {
                    s[qf][kf] = MFMA(qah[qf][dc], kbh[kf][dc], s[qf][kf]);
                    s[qf][kf] = MFMA(qah[qf][dc], kbl[kf][dc], s[qf][kf]);
                    s[qf][kf] = MFMA(qal[qf][dc], kbh[kf][dc], s[qf][kf]);
                }
        #pragma unroll
        for (int qf = 0; qf < 2; ++qf)
            #pragma unroll
            for (int kf = 0; kf < 4; ++kf)
                #pragma unroll
                for (int r = 0; r < 4; ++r) {
                    int q = q0 + w * 32 + 16 * qf + lg * 4 + r;
                    int kc = k0 + 16 * kf + l15;
                    if (q >= kc && q < T_SEQ)
                        csum[kf] += __expf(s[qf][kf][r] * 0.125f);
                }
    }
    #pragma unroll
    for (int kf = 0; kf < 4; ++kf) {
        csum[kf] += __shfl_xor(csum[kf], 16);
        csum[kf] += __shfl_xor(csum[kf], 32);
    }
    if (lg == 0) {
        #pragma unroll
        for (int kf = 0; kf < 4; ++kf) red[w][16 * kf + l15] = csum[kf];
    }
    __syncthreads();
    if (tid < 64) {
        float d = red[0][tid] + red[1][tid] + red[2][tid] + red[3][tid];
        Dp[((size_t)qs * NB + b) * T_SEQ + k0 + tid] = d;
    }
}

// ---------------------------------------------------------------------------
// Kernel 3: Dinv = 1 / (sum of 4 Dp partials)
// ---------------------------------------------------------------------------
__global__ __launch_bounds__(256) void dinv_kernel(
    const float* __restrict__ Dp, float* __restrict__ Dinv)
{
    int i = blockIdx.x * 256 + threadIdx.x;        // 32768 threads
    const int S = NB * T_SEQ;
    float d = Dp[i] + Dp[S + i] + Dp[2 * S + i] + Dp[3 * S + i];
    Dinv[i] = 1.0f / d;
}

// ---------------------------------------------------------------------------
// Kernel 4: O = (exp(S)/d) @ V.  S^T = MFMA(K, Q^T): all K/Q/V frags direct
// from global; P transposed through per-wave-private swizzled LDS (8KB/wave).
// Zero barriers in the k-loop.  grid 512 (half/qt-paired k-split).
// FIX (r4): PV read index must XOR the FULL k offset:
//   (32*kb + 8*lg) ^ swz   — NOT 32*kb + (8*lg ^ swz); the latter walks out
// of the 64-short row whenever swz has bit 5 set (qloc & 4), which corrupted
// P for half of all q rows in round 3.
// ---------------------------------------------------------------------------
__global__ __launch_bounds__(256, 2) void out_kernel(
    const short* __restrict__ Qhi, const short* __restrict__ Qlo,
    const short* __restrict__ Khi, const short* __restrict__ Klo,
    const short* __restrict__ VThi, const short* __restrict__ VTlo,
    const float* __restrict__ Dinv,
    float* __restrict__ out, float* __restrict__ Op1)
{
    __shared__ short pt[4][4096];     // [wave][hi 2048 | lo 2048] shorts
    const int tid = threadIdx.x;
    const int lane = tid & 63, w = tid >> 6;
    const int l15 = lane & 15, lg = lane >> 4;
    const int bx = blockIdx.x;
    const int half = bx >> 8;
    const int jj = bx & 255;
    const int b = jj >> 5;
    const int ii = jj & 31;
    const int qt = half ? 31 - ii : ii;
    const int q0 = qt * 128;
    const size_t bT = (size_t)b * T_SEQ;
    short* ptw = pt[w];

    bf8 qh[2][2], ql[2][2];           // persistent Q fragments (B-operand)
    #pragma unroll
    for (int qf = 0; qf < 2; ++qf)
        #pragma unroll
        for (int dc = 0; dc < 2; ++dc) {
            size_t o = (bT + q0 + 32 * w + 16 * qf + l15) * 64 + dc * 32 + lg * 8;
            qh[qf][dc] = *reinterpret_cast<const bf8*>(Qhi + o);
            ql[qf][dc] = *reinterpret_cast<const bf8*>(Qlo + o);
        }
    f4 oacc[2][4] = {};

    for (int k0 = half * 64; k0 < q0 + 128; k0 += 128) {
        // --- S^T = K · Q^T (split-3) ---
        f4 st[4][2] = {};
        #pragma unroll
        for (int dc = 0; dc < 2; ++dc) {
            bf8 kh[4], kl[4];
            #pragma unroll
            for (int kf = 0; kf < 4; ++kf) {
                size_t o = (bT + k0 + 16 * kf + l15) * 64 + dc * 32 + lg * 8;
                kh[kf] = *reinterpret_cast<const bf8*>(Khi + o);
                kl[kf] = *reinterpret_cast<const bf8*>(Klo + o);
            }
            #pragma unroll
            for (int kf = 0; kf < 4; ++kf)
                #pragma unroll
                for (int qf = 0; qf < 2; ++qf) {
                    st[kf][qf] = MFMA(kh[kf], qh[qf][dc], st[kf][qf]);
                    st[kf][qf] = MFMA(kh[kf], ql[qf][dc], st[kf][qf]);
                    st[kf][qf] = MFMA(kl[kf], qh[qf][dc], st[kf][qf]);
                }
        }
        // --- P = exp(S)/d, bf16 hi/lo, per-wave swizzled LDS (transpose) ---
        #pragma unroll
        for (int kf = 0; kf < 4; ++kf) {
            float4 di = *reinterpret_cast<const float4*>(
                Dinv + b * T_SEQ + k0 + 16 * kf + 4 * lg);
            const float* dip = reinterpret_cast<const float*>(&di);
            #pragma unroll
            for (int qf = 0; qf < 2; ++qf) {
                int qloc = 16 * qf + l15;
                int q = q0 + 32 * w + qloc;
                unsigned short hb[4], lb[4];
                #pragma unroll
                for (int r = 0; r < 4; ++r) {
                    int kg = k0 + 16 * kf + 4 * lg + r;
                    float p = (q >= kg) ? __expf(st[kf][qf][r] * 0.125f) * dip[r]
                                        : 0.f;
                    short h = f2bf(p);
                    hb[r] = (unsigned short)h;
                    lb[r] = (unsigned short)f2bf(p - bf2f(h));
                }
                int sidx = qloc * 64 + (((16 * kf + 4 * lg) ^ ((qloc & 7) << 3)));
                *reinterpret_cast<int2*>(&ptw[sidx]) = make_int2(
                    (int)((unsigned)hb[0] | ((unsigned)hb[1] << 16)),
                    (int)((unsigned)hb[2] | ((unsigned)hb[3] << 16)));
                *reinterpret_cast<int2*>(&ptw[2048 + sidx]) = make_int2(
                    (int)((unsigned)lb[0] | ((unsigned)lb[1] << 16)),
                    (int)((unsigned)lb[2] | ((unsigned)lb[3] << 16)));
            }
        }
        // --- PV: O += P · V (split-3) ---
        #pragma unroll
        for (int kb = 0; kb < 2; ++kb) {
            bf8 vh[4], vl[4];
            #pragma unroll
            for (int hf = 0; hf < 4; ++hf) {
                size_t o = ((size_t)b * 64 + 16 * hf + l15) * T_SEQ
                         + k0 + 32 * kb + 8 * lg;
                vh[hf] = *reinterpret_cast<const bf8*>(VThi + o);
                vl[hf] = *reinterpret_cast<const bf8*>(VTlo + o);
            }
            #pragma unroll
            for (int qf = 0; qf < 2; ++qf) {
                int qloc = 16 * qf + l15;
                int ridx = qloc * 64 + (((32 * kb + 8 * lg) ^ ((qloc & 7) << 3)));
                bf8 pa = *reinterpret_cast<const bf8*>(&ptw[ridx]);
                bf8 pb = *reinterpret_cast<const bf8*>(&ptw[2048 + ridx]);
                #pragma unroll
                for (int hf = 0; hf < 4; ++hf) {
                    oacc[qf][hf] = MFMA(pa, vh[hf], oacc[qf][hf]);
                    oacc[qf][hf] = MFMA(pa, vl[hf], oacc[qf][hf]);
                    oacc[qf][hf] = MFMA(pb, vh[hf], oacc[qf][hf]);
                }
            }
        }
    }
    float* dst = half ? Op1 : out;
    #pragma unroll
    for (int qf = 0; qf < 2; ++qf)
        #pragma unroll
        for (int hf = 0; hf < 4; ++hf)
            #pragma unroll
            for (int r = 0; r < 4; ++r) {
                int q = q0 + 32 * w + 16 * qf + 4 * lg + r;
                dst[(bT + q) * 64 + 16 * hf + l15] = oacc[qf][hf][r];
            }
}

// ---------------------------------------------------------------------------
// Kernel 5: out += Op1 (deterministic k-split combine)
// ---------------------------------------------------------------------------
__global__ __launch_bounds__(256) void combine_kernel(
    float* __restrict__ out, const float* __restrict__ Op1)
{
    size_t idx = ((size_t)blockIdx.x * 256 + threadIdx.x) * 4;
    float4 a = *reinterpret_cast<const float4*>(out + idx);
    float4 c = *reinterpret_cast<const float4*>(Op1 + idx);
    *reinterpret_cast<float4*>(out + idx) =
        make_float4(a.x + c.x, a.y + c.y, a.z + c.z, a.w + c.w);
}

extern "C" void kernel_launch(void* const* d_in, const int* in_sizes, int n_in,
                              void* d_out, int out_size, void* d_ws, size_t ws_size,
                              hipStream_t stream) {
    (void)in_sizes; (void)n_in; (void)out_size; (void)ws_size;
    const float* x  = (const float*)d_in[0];
    const float* Wk = (const float*)d_in[1];
    const float* Wq = (const float*)d_in[2];
    const float* Wv = (const float*)d_in[3];
    float* out = (float*)d_out;
    char* w8 = (char*)d_ws;

    const size_t SZ = (size_t)NB * T_SEQ * CHEAD * sizeof(short);  // 4 MB
    short* Qhi  = (short*)(w8);
    short* Qlo  = (short*)(w8 + SZ);
    short* Khi  = (short*)(w8 + 2 * SZ);
    short* Klo  = (short*)(w8 + 3 * SZ);
    short* VThi = (short*)(w8 + 4 * SZ);
    short* VTlo = (short*)(w8 + 5 * SZ);
    short* Wp   = (short*)(w8 + 6 * SZ);                   // 786,432 B
    float* Dp   = (float*)(w8 + 6 * SZ + 786432);          // 524,288 B
    float* Dinv = (float*)(w8 + 6 * SZ + 786432 + 524288); // 131,072 B
    float* Op1  = (float*)(w8 + 6 * SZ + 786432 + 524288 + 131072);  // 8 MB
    // total ws use ≈ 33.4 MB

    hipLaunchKernelGGL(wsplit_kernel, dim3(768), dim3(256), 0, stream,
                       Wk, Wq, Wv, Wp);
    hipLaunchKernelGGL(proj_kernel, dim3(512), dim3(128), 0, stream,
                       x, Wp, Qhi, Qlo, Khi, Klo, VThi, VTlo);
    hipLaunchKernelGGL(colsum_kernel, dim3(64, 4, NB), dim3(256), 0, stream,
                       Qhi, Qlo, Khi, Klo, Dp);
    hipLaunchKernelGGL(dinv_kernel, dim3(128), dim3(256), 0, stream,
                       Dp, Dinv);
    hipLaunchKernelGGL(out_kernel, dim3(512), dim3(256), 0, stream,
                       Qhi, Qlo, Khi, Klo, VThi, VTlo, Dinv, out, Op1);
    hipLaunchKernelGGL(combine_kernel, dim3(2048), dim3(256), 0, stream,
                       out, Op1);
}